// Round 8
// baseline (95.004 us; speedup 1.0000x reference)
//
#include <hip/hip_runtime.h>

// TT Q-gather v9 — SINGLE kernel, ZERO workspace, LDS core-paging.
//
//   v = G0[s0,:]                    (fp32, 2 divergent 16B loads, exact)
//   for k=1..6: v = v @ Gk[:,sk,:]  (bf16 8x8 from LDS; cores paged through
//                                    a 64 KB double buffer, built on the fly
//                                    from the fp32 inputs)
//   q = v . G7[:,a7]                (fp32 from 8 KB LDS copy, exact)
//
// R7 post-mortem: v8's hand pipeline == v4 (90 us) -> the chain was never
// the binding constraint. Decomposition (R5: build+gaps=15; R2: 22) puts
// the non-spilled gather at ~30us vs ~5us pipe model, constant across 3
// different chain structures. Common to all: the fill(42us, stream-serial)
// -> build_tables -> gap -> gather structure with ws tables read through
// cold caches. v9 deletes the structure: no ws (maybe no fill), no build
// kernel, no gap; staging reads come from the never-poisoned input
// buffers. 72 KB LDS -> 2 blocks/CU = 4 waves/SIMD (2x v8). Only G1..G6
// are bf16-rounded now (endpoints exact) -> absmax stays ~1e-22.
//
// LDS (per block, 72 KB): buf0/buf1 16384 ushorts each (32 KB x2),
//                         g7s 2048 fp32 (8 KB)

#define NN 256
#define RR 8
#define NR 2048   // N * R

__device__ __forceinline__ unsigned short f2bf_rne(float f) {
    unsigned int u = __float_as_uint(f);
    u += 0x7FFFu + ((u >> 16) & 1u);
    return (unsigned short)(u >> 16);
}

__device__ __forceinline__ uint4 pack8bf(const float* a) {
    return make_uint4(
        f2bf_rne(a[0]) | ((unsigned int)f2bf_rne(a[1]) << 16),
        f2bf_rne(a[2]) | ((unsigned int)f2bf_rne(a[3]) << 16),
        f2bf_rne(a[4]) | ((unsigned int)f2bf_rne(a[5]) << 16),
        f2bf_rne(a[6]) | ((unsigned int)f2bf_rne(a[7]) << 16));
}

#define BF2F_LO(u) __uint_as_float((u) << 16)
#define BF2F_HI(u) __uint_as_float((u) & 0xFFFF0000u)

// stage one core from global fp32 into LDS buffer nc (compile-time), bf16.
// 512 threads x 4 (r,n)-pairs; coalesced 2x float4 per pair; conflict-free
// ds_write_b128 (consecutive n -> consecutive 16B slots).
#define STAGE_NEXT(nc, Gsrc)                                                \
    do {                                                                    \
        _Pragma("unroll") for (int i = 0; i < 4; ++i) {                     \
            const int p = (i << 9) + t;       /* 0..2047 */                 \
            const int r = p >> 8, n = p & 255;                              \
            const float4* sp = (const float4*)((Gsrc) + r * NR + n * RR);   \
            float4 x = sp[0], y = sp[1];                                    \
            float a8[8] = {x.x, x.y, x.z, x.w, y.x, y.y, y.z, y.w};         \
            lbuf[(nc) * 2048 + r * 256 + n] = pack8bf(a8);                  \
        }                                                                   \
    } while (0)

// accumulate row-pair (2rp, 2rp+1) held in q0,q1 with weights v[2rp],v[2rp+1]
#define FPX(q0, q1, rp)                                                     \
    do {                                                                    \
        const float wa = v[2 * (rp)], wb = v[2 * (rp) + 1];                 \
        acc[0] += wa * BF2F_LO(q0.x); acc[0] += wb * BF2F_LO(q1.x);         \
        acc[1] += wa * BF2F_HI(q0.x); acc[1] += wb * BF2F_HI(q1.x);         \
        acc[2] += wa * BF2F_LO(q0.y); acc[2] += wb * BF2F_LO(q1.y);         \
        acc[3] += wa * BF2F_HI(q0.y); acc[3] += wb * BF2F_HI(q1.y);         \
        acc[4] += wa * BF2F_LO(q0.z); acc[4] += wb * BF2F_LO(q1.z);         \
        acc[5] += wa * BF2F_HI(q0.z); acc[5] += wb * BF2F_HI(q1.z);         \
        acc[6] += wa * BF2F_LO(q0.w); acc[6] += wb * BF2F_LO(q1.w);         \
        acc[7] += wa * BF2F_HI(q0.w); acc[7] += wb * BF2F_HI(q1.w);         \
    } while (0)

// one chain stage: v = v @ core-in-buffer-c, column-slice nidx.
// 3-buffer-ish rotation inside the phase keeps live rows <= 4 uint4.
#define PHASE_CHAIN(c, nidx)                                                \
    do {                                                                    \
        const uint4* mp = lbuf + (c) * 2048 + (nidx);                       \
        uint4 P0 = mp[0],   P1 = mp[256];                                   \
        uint4 Q0 = mp[512], Q1 = mp[768];                                   \
        float acc[8] = {0.f,0.f,0.f,0.f,0.f,0.f,0.f,0.f};                   \
        FPX(P0, P1, 0);                                                     \
        P0 = mp[1024]; P1 = mp[1280];                                       \
        FPX(Q0, Q1, 1);                                                     \
        Q0 = mp[1536]; Q1 = mp[1792];                                       \
        FPX(P0, P1, 2);                                                     \
        FPX(Q0, Q1, 3);                                                     \
        _Pragma("unroll") for (int i = 0; i < 8; ++i) v[i] = acc[i];        \
    } while (0)

__global__ __launch_bounds__(512, 2) void tt_fused(
    const float* __restrict__ G0, const float* __restrict__ G1,
    const float* __restrict__ G2, const float* __restrict__ G3,
    const float* __restrict__ G4, const float* __restrict__ G5,
    const float* __restrict__ G6, const float* __restrict__ G7,
    const int* __restrict__ states, const int* __restrict__ actions,
    float* __restrict__ out, int B) {
    __shared__ unsigned short lut[2 * 16384];   // 64 KB: double buffer
    __shared__ float g7s[2048];                 // 8 KB: G7 fp32

    uint4* lbuf = (uint4*)lut;
    const int t = threadIdx.x;
    const int b = blockIdx.x * 512 + t;
    const bool active = (b < B);
    const int base = active ? b * 7 : 0;
    const int s0 = states[base + 0] & 255;
    const int s1 = states[base + 1] & 255;
    const int s2 = states[base + 2] & 255;
    const int s3 = states[base + 3] & 255;
    const int s4 = states[base + 4] & 255;
    const int s5 = states[base + 5] & 255;
    const int s6 = states[base + 6] & 255;
    const int a7 = actions[active ? b : 0] & 255;

    // v init: exact fp32 row of G0 (8 KB, L2-hot); issued early
    const float4* g0p = (const float4*)(G0 + s0 * RR);
    const float4 v0a = g0p[0], v0b = g0p[1];

    // prologue: G7 fp32 copy (2048 floats = 1 float4/thread) + G1 -> buf0
    ((float4*)g7s)[t] = ((const float4*)G7)[t];
    STAGE_NEXT(0, G1);
    __syncthreads();

    float v[8] = {v0a.x, v0a.y, v0a.z, v0a.w, v0b.x, v0b.y, v0b.z, v0b.w};

    // 6 paged phases: stage core k+1 into the other buffer while
    // contracting core k from the current one; one barrier per phase.
    STAGE_NEXT(1, G2);  PHASE_CHAIN(0, s1);  __syncthreads();
    STAGE_NEXT(0, G3);  PHASE_CHAIN(1, s2);  __syncthreads();
    STAGE_NEXT(1, G4);  PHASE_CHAIN(0, s3);  __syncthreads();
    STAGE_NEXT(0, G5);  PHASE_CHAIN(1, s4);  __syncthreads();
    STAGE_NEXT(1, G6);  PHASE_CHAIN(0, s5);  __syncthreads();
                        PHASE_CHAIN(1, s6);

    // epilogue: exact fp32 dot with G7[:, a7]
    float q = 0.f;
#pragma unroll
    for (int r = 0; r < RR; ++r) q += v[r] * g7s[r * NN + a7];

    if (active) out[b] = q;
}

extern "C" void kernel_launch(void* const* d_in, const int* in_sizes, int n_in,
                              void* d_out, int out_size, void* d_ws, size_t ws_size,
                              hipStream_t stream) {
    const float* G0 = (const float*)d_in[0];
    const float* G1 = (const float*)d_in[1];
    const float* G2 = (const float*)d_in[2];
    const float* G3 = (const float*)d_in[3];
    const float* G4 = (const float*)d_in[4];
    const float* G5 = (const float*)d_in[5];
    const float* G6 = (const float*)d_in[6];
    const float* G7 = (const float*)d_in[7];
    const int* states  = (const int*)d_in[8];
    const int* actions = (const int*)d_in[9];
    float* out = (float*)d_out;
    int B = in_sizes[9];

    (void)d_ws; (void)ws_size;   // workspace intentionally unused

    hipLaunchKernelGGL(tt_fused, dim3((B + 511) / 512), dim3(512), 0, stream,
                       G0, G1, G2, G3, G4, G5, G6, G7,
                       states, actions, out, B);
}

// Round 9
// 90.355 us; speedup vs baseline: 1.0514x; 1.0514x over previous
//
#include <hip/hip_runtime.h>

// TT Q-gather v10 — v8 shell+chain, 2 elements/thread: staging amortized 2x.
//
//   v = V01[s0][s1][:]        (1 MB global table, L2-resident)
//   for k=2..5: v = v @ Gk[:,sk,:]   (bf16, from 128 KB LDS, prebuilt image)
//   q = v . U67[s6][a7][:]    (1 MB global table, L2-resident)
//
// R8 post-mortem: v9 single-kernel paging = ~45us (6 barrier-separated
// stage phases at 1 block/CU expose staging latency 6x) -> reverted.
// v8 == v4 == ~90 total pins the 2-kernel gather at ~33us and shows the
// chain pipeline is NOT the constraint. Remaining suspects: per-CU double
// staging round (512 blocks / 256 CUs, each serially staging 128 KB) or
// fixed harness overhead. v10 keeps v8's proven chain and halves the
// grid: 256 blocks, 2 sequential elements/thread -> ONE staging per CU,
// half the block prologues. Regs: v8 peak + ~24 (4 endpoint uint4 + 2nd
// index set up front) < 128 tier. If total doesn't move, kernels are
// minor and the floor is fill+reset machinery -> declare next round.
//
// ws layout (ushort units):
//   V01 @ 0       : [s0][s1][s] 256*256*8   (1 MB)
//   U67 @ 524288  : [s6][a7][r] 256*256*8   (1 MB)
//   Gt  @ 1048576 : [k][r][n][s] 4*8*256*8  (256 KB) -- LDS image, r-major

#define NN 256
#define RR 8
#define NR 2048   // N * R
#define U67_OFF 524288
#define GT_OFF  1048576
#define GT_CORE 16384   // ushorts per core (32 KB)

__device__ __forceinline__ unsigned short f2bf_rne(float f) {
    unsigned int u = __float_as_uint(f);
    u += 0x7FFFu + ((u >> 16) & 1u);
    return (unsigned short)(u >> 16);
}

__device__ __forceinline__ uint4 pack8bf(const float* a) {
    return make_uint4(
        f2bf_rne(a[0]) | ((unsigned int)f2bf_rne(a[1]) << 16),
        f2bf_rne(a[2]) | ((unsigned int)f2bf_rne(a[3]) << 16),
        f2bf_rne(a[4]) | ((unsigned int)f2bf_rne(a[5]) << 16),
        f2bf_rne(a[6]) | ((unsigned int)f2bf_rne(a[7]) << 16));
}

// 544 blocks x 256 threads:
//   0..255   -> V01 row n0
//   256..511 -> U67 row n6
//   512..543 -> transpose G2..G5 into r-major bf16 image (8 blocks/core)
__global__ __launch_bounds__(256) void build_tables(
    const float* __restrict__ G0, const float* __restrict__ G1,
    const float* __restrict__ G2, const float* __restrict__ G3,
    const float* __restrict__ G4, const float* __restrict__ G5,
    const float* __restrict__ G6, const float* __restrict__ G7,
    unsigned short* __restrict__ wsb) {
    const int t = threadIdx.x;
    const int bid = blockIdx.x;

    if (bid < NN) {
        // V01[n0][n1][s] = sum_r G0[n0,r] * G1[r,n1,s]
        const int n0 = bid, n1 = t;
        float acc[RR] = {0.f,0.f,0.f,0.f,0.f,0.f,0.f,0.f};
#pragma unroll
        for (int r = 0; r < RR; ++r) {
            float ar = G0[n0 * RR + r];
            const float4* p = (const float4*)(G1 + r * NR + n1 * RR);
            float4 x = p[0], y = p[1];
            acc[0] += ar * x.x; acc[1] += ar * x.y;
            acc[2] += ar * x.z; acc[3] += ar * x.w;
            acc[4] += ar * y.x; acc[5] += ar * y.y;
            acc[6] += ar * y.z; acc[7] += ar * y.w;
        }
        *(uint4*)(wsb + n0 * 2048 + n1 * 8) = pack8bf(acc);
    } else if (bid < 2 * NN) {
        // U67[n6][n7][r] = sum_s G6[r,n6,s] * G7[s,n7]
        const int n6 = bid - NN, n7 = t;
        float g7v[RR];
#pragma unroll
        for (int s = 0; s < RR; ++s) g7v[s] = G7[s * NN + n7];
        float u[RR];
#pragma unroll
        for (int r = 0; r < RR; ++r) {
            float acc = 0.f;
#pragma unroll
            for (int s = 0; s < RR; ++s)
                acc += G6[r * NR + n6 * RR + s] * g7v[s];
            u[r] = acc;
        }
        *(uint4*)(wsb + U67_OFF + n6 * 2048 + n7 * 8) = pack8bf(u);
    } else {
        // transpose G2..G5 -> Gt[k][r][n][s] bf16 (r-major image)
        const int q = bid - 2 * NN;        // 0..31
        const int k = q >> 3;              // 0..3 -> G2..G5
        const int chunk = q & 7;
        const float* __restrict__ Gk =
            (k == 0) ? G2 : (k == 1) ? G3 : (k == 2) ? G4 : G5;
        const int n = chunk * 32 + (t >> 3);
        const int r = t & 7;
        const float4* src = (const float4*)(Gk + r * NR + n * RR);
        float4 x = src[0], y = src[1];
        float a[8] = {x.x, x.y, x.z, x.w, y.x, y.y, y.z, y.w};
        *(uint4*)(wsb + GT_OFF + k * GT_CORE + r * 2048 + n * 8) = pack8bf(a);
    }
}

#define BF2F_LO(u) __uint_as_float((u) << 16)
#define BF2F_HI(u) __uint_as_float((u) & 0xFFFF0000u)

// load row-pair (r=2rp, 2rp+1) of core k, column-slice n into q0,q1
#define LP(q0, q1, k, nk, rp)                                               \
    do {                                                                    \
        const uint4* _p = l4 + (k) * 2048 + (nk) + (rp) * 512;              \
        q0 = _p[0];                                                         \
        q1 = _p[256];                                                       \
    } while (0)

// accumulate row-pair rp with weights v[2rp], v[2rp+1] into acc[0..7]
#define FP(q0, q1, rp)                                                      \
    do {                                                                    \
        const float wa = v[2 * (rp)], wb = v[2 * (rp) + 1];                 \
        acc[0] += wa * BF2F_LO(q0.x); acc[0] += wb * BF2F_LO(q1.x);         \
        acc[1] += wa * BF2F_HI(q0.x); acc[1] += wb * BF2F_HI(q1.x);         \
        acc[2] += wa * BF2F_LO(q0.y); acc[2] += wb * BF2F_LO(q1.y);         \
        acc[3] += wa * BF2F_HI(q0.y); acc[3] += wb * BF2F_HI(q1.y);         \
        acc[4] += wa * BF2F_LO(q0.z); acc[4] += wb * BF2F_LO(q1.z);         \
        acc[5] += wa * BF2F_HI(q0.z); acc[5] += wb * BF2F_HI(q1.z);         \
        acc[6] += wa * BF2F_LO(q0.w); acc[6] += wb * BF2F_LO(q1.w);         \
        acc[7] += wa * BF2F_HI(q0.w); acc[7] += wb * BF2F_HI(q1.w);         \
    } while (0)

#define ENDST                                                               \
    do {                                                                    \
        _Pragma("unroll") for (int i = 0; i < 8; ++i) {                     \
            v[i] = acc[i]; acc[i] = 0.f;                                    \
        }                                                                   \
    } while (0)

// full per-element chain: init v from uvx, 16-step pipelined 4-stage chain
// over column slices (c2,c3,c4,c5), dot with uex, store to out[bx] if actx.
#define CHAIN_FULL(uvx, uex, c2, c3, c4, c5, bx, actx)                      \
    do {                                                                    \
        float v[8], acc[8];                                                 \
        v[0] = BF2F_LO(uvx.x); v[1] = BF2F_HI(uvx.x);                       \
        v[2] = BF2F_LO(uvx.y); v[3] = BF2F_HI(uvx.y);                       \
        v[4] = BF2F_LO(uvx.z); v[5] = BF2F_HI(uvx.z);                       \
        v[6] = BF2F_LO(uvx.w); v[7] = BF2F_HI(uvx.w);                       \
        _Pragma("unroll") for (int i = 0; i < 8; ++i) acc[i] = 0.f;         \
        uint4 X0, X1, Y0, Y1, Z0, Z1;                                       \
        LP(X0, X1, 0, c2, 0);                                               \
        LP(Y0, Y1, 0, c2, 1);                                               \
        LP(Z0, Z1, 0, c2, 2);  FP(X0, X1, 0);                               \
        LP(X0, X1, 0, c2, 3);  FP(Y0, Y1, 1);                               \
        LP(Y0, Y1, 1, c3, 0);  FP(Z0, Z1, 2);                               \
        LP(Z0, Z1, 1, c3, 1);  FP(X0, X1, 3);  ENDST;                       \
        LP(X0, X1, 1, c3, 2);  FP(Y0, Y1, 0);                               \
        LP(Y0, Y1, 1, c3, 3);  FP(Z0, Z1, 1);                               \
        LP(Z0, Z1, 2, c4, 0);  FP(X0, X1, 2);                               \
        LP(X0, X1, 2, c4, 1);  FP(Y0, Y1, 3);  ENDST;                       \
        LP(Y0, Y1, 2, c4, 2);  FP(Z0, Z1, 0);                               \
        LP(Z0, Z1, 2, c4, 3);  FP(X0, X1, 1);                               \
        LP(X0, X1, 3, c5, 0);  FP(Y0, Y1, 2);                               \
        LP(Y0, Y1, 3, c5, 1);  FP(Z0, Z1, 3);  ENDST;                       \
        LP(Z0, Z1, 3, c5, 2);  FP(X0, X1, 0);                               \
        LP(X0, X1, 3, c5, 3);  FP(Y0, Y1, 1);                               \
                               FP(Z0, Z1, 2);                               \
                               FP(X0, X1, 3);  ENDST;                       \
        float q = v[0] * BF2F_LO(uex.x) + v[1] * BF2F_HI(uex.x)             \
                + v[2] * BF2F_LO(uex.y) + v[3] * BF2F_HI(uex.y)             \
                + v[4] * BF2F_LO(uex.z) + v[5] * BF2F_HI(uex.z)             \
                + v[6] * BF2F_LO(uex.w) + v[7] * BF2F_HI(uex.w);            \
        if (actx) out[bx] = q;                                              \
    } while (0)

__global__ __launch_bounds__(512, 2) void tt_gather(
    const unsigned short* __restrict__ wsb,
    const int* __restrict__ states, const int* __restrict__ actions,
    float* __restrict__ out, int B) {
    __shared__ unsigned short lut[4 * GT_CORE];   // 128 KB

    const int t = threadIdx.x;
    const int bA = blockIdx.x * 1024 + t;          // element A
    const int bB = bA + 512;                       // element B
    const bool actA = (bA < B), actB = (bB < B);
    const int baseA = actA ? bA * 7 : 0;
    const int baseB = actB ? bB * 7 : 0;

    const int a0 = states[baseA + 0] & 255, e0 = states[baseB + 0] & 255;
    const int a1 = states[baseA + 1] & 255, e1 = states[baseB + 1] & 255;
    const int a2 = states[baseA + 2] & 255, e2 = states[baseB + 2] & 255;
    const int a3 = states[baseA + 3] & 255, e3 = states[baseB + 3] & 255;
    const int a4 = states[baseA + 4] & 255, e4 = states[baseB + 4] & 255;
    const int a5 = states[baseA + 5] & 255, e5 = states[baseB + 5] & 255;
    const int a6 = states[baseA + 6] & 255, e6 = states[baseB + 6] & 255;
    const int aa = actions[actA ? bA : 0] & 255;
    const int ea = actions[actB ? bB : 0] & 255;

    // all 4 endpoint loads issued up front (MLP); consumed after barrier
    const uint4 uvA = *(const uint4*)(wsb + a0 * 2048 + a1 * 8);
    const uint4 ueA = *(const uint4*)(wsb + U67_OFF + a6 * 2048 + aa * 8);
    const uint4 uvB = *(const uint4*)(wsb + e0 * 2048 + e1 * 8);
    const uint4 ueB = *(const uint4*)(wsb + U67_OFF + e6 * 2048 + ea * 8);

    // stage prebuilt bf16 Gt image: pure copy, 16 uint4 per thread.
    // 256 blocks -> exactly ONE staging per CU (v8 paid this twice).
    {
        const uint4* src = (const uint4*)(wsb + GT_OFF);
        uint4* dst = (uint4*)lut;
#pragma unroll
        for (int i = 0; i < 16; ++i) dst[t + (i << 9)] = src[t + (i << 9)];
    }
    __syncthreads();

    const uint4* l4 = (const uint4*)lut;

    CHAIN_FULL(uvA, ueA, a2, a3, a4, a5, bA, actA);
    CHAIN_FULL(uvB, ueB, e2, e3, e4, e5, bB, actB);
}

extern "C" void kernel_launch(void* const* d_in, const int* in_sizes, int n_in,
                              void* d_out, int out_size, void* d_ws, size_t ws_size,
                              hipStream_t stream) {
    const float* G0 = (const float*)d_in[0];
    const float* G1 = (const float*)d_in[1];
    const float* G2 = (const float*)d_in[2];
    const float* G3 = (const float*)d_in[3];
    const float* G4 = (const float*)d_in[4];
    const float* G5 = (const float*)d_in[5];
    const float* G6 = (const float*)d_in[6];
    const float* G7 = (const float*)d_in[7];
    const int* states  = (const int*)d_in[8];
    const int* actions = (const int*)d_in[9];
    float* out = (float*)d_out;
    int B = in_sizes[9];

    unsigned short* wsb = (unsigned short*)d_ws;   // ~2.25 MB used

    hipLaunchKernelGGL(build_tables, dim3(2 * NN + 32), dim3(256), 0, stream,
                       G0, G1, G2, G3, G4, G5, G6, G7, wsb);

    hipLaunchKernelGGL(tt_gather, dim3((B + 1023) / 1024), dim3(512), 0, stream,
                       wsb, states, actions, out, B);
}